// Round 1
// baseline (1990.100 us; speedup 1.0000x reference)
//
#include <hip/hip_runtime.h>
#include <cstdint>
#include <cstddef>

#define NN 50000
#define NE 800000
#define HID 64
#define INF_ 128
#define BN_EPS 1e-5f

// ---------------- graph prep ----------------

__global__ void count_k(const int* __restrict__ dst, int* __restrict__ cnt) {
    int e = blockIdx.x * blockDim.x + threadIdx.x;
    if (e < NE) atomicAdd(&cnt[dst[e]], 1);
}

__global__ void dinv_k(const int* __restrict__ cnt, float* __restrict__ dinv) {
    int n = blockIdx.x * blockDim.x + threadIdx.x;
    if (n < NN) dinv[n] = rsqrtf((float)(cnt[n] + 1));   // +1 self-loop, deg>0 always
}

// single-block exclusive scan of cnt -> offs (offs[NN] = NE)
__global__ void scan_k(const int* __restrict__ cnt, int* __restrict__ offs) {
    __shared__ int part[1024];
    int t = threadIdx.x;
    const int SEG = (NN + 1023) / 1024;   // 49
    int lo = t * SEG;
    int hi = lo + SEG; if (hi > NN) hi = NN; if (lo > NN) lo = NN;
    int s = 0;
    for (int i = lo; i < hi; ++i) s += cnt[i];
    part[t] = s;
    __syncthreads();
    for (int d = 1; d < 1024; d <<= 1) {
        int v = (t >= d) ? part[t - d] : 0;
        __syncthreads();
        part[t] += v;
        __syncthreads();
    }
    int run = (t == 0) ? 0 : part[t - 1];
    for (int i = lo; i < hi; ++i) { offs[i] = run; run += cnt[i]; }
    if (t == 1023) offs[NN] = run;
}

__global__ void scatter_k(const int* __restrict__ src, const int* __restrict__ dst,
                          const int* __restrict__ offs, int* __restrict__ cursor,
                          const float* __restrict__ dinv,
                          int* __restrict__ csrc, float* __restrict__ cw) {
    int e = blockIdx.x * blockDim.x + threadIdx.x;
    if (e < NE) {
        int s = src[e], d = dst[e];
        int pos = offs[d] + atomicAdd(&cursor[d], 1);
        csrc[pos] = s;
        cw[pos] = dinv[s] * dinv[d];
    }
}

// ---------------- dense matmul: Y[N,64] = X[N,K] @ W[K,64] ----------------

template <int K>
__global__ void mm_k(const float* __restrict__ X, const float* __restrict__ W,
                     float* __restrict__ Y) {
    __shared__ float Ws[K * 64];
    for (int i = threadIdx.x; i < K * 64; i += blockDim.x) Ws[i] = W[i];
    __syncthreads();
    int lane = threadIdx.x & 63;
    int wid = blockIdx.x * (blockDim.x >> 6) + (threadIdx.x >> 6);
    int nw = gridDim.x * (blockDim.x >> 6);
    for (int n = wid; n < NN; n += nw) {
        float acc = 0.f;
        for (int k0 = 0; k0 < K; k0 += 64) {
            float xv = X[(size_t)n * K + k0 + lane];
#pragma unroll
            for (int j = 0; j < 64; ++j) {
                float xk = __shfl(xv, j, 64);
                acc = fmaf(xk, Ws[(k0 + j) * 64 + lane], acc);
            }
        }
        Y[(size_t)n * 64 + lane] = acc;
    }
}

// ---------------- propagate + bias + BN-stat accumulation ----------------
// Y[n] = dinv[n]^2 * X[n] + sum_e w_e X[src_e] + bias ; stats[0:64]+=sum, [64:128]+=sumsq
__global__ void prop_stats_k(const float* __restrict__ X,
                             const int* __restrict__ offs, const int* __restrict__ csrc,
                             const float* __restrict__ cw, const float* __restrict__ dinv,
                             const float* __restrict__ bias,
                             float* __restrict__ Y, float* __restrict__ stats) {
    int lane = threadIdx.x & 63;
    int wave = threadIdx.x >> 6;
    int wid = blockIdx.x * 4 + wave;            // blockDim must be 256
    int nw = gridDim.x * 4;
    float s1 = 0.f, s2 = 0.f;
    for (int n = wid; n < NN; n += nw) {
        float dn = dinv[n];
        float acc = dn * dn * X[(size_t)n * 64 + lane];
        int e0 = offs[n], e1 = offs[n + 1];
        for (int e = e0; e < e1; ++e) {
            int s = csrc[e];
            float w = cw[e];
            acc = fmaf(w, X[(size_t)s * 64 + lane], acc);
        }
        acc += bias[lane];
        Y[(size_t)n * 64 + lane] = acc;
        s1 += acc;
        s2 += acc * acc;
    }
    __shared__ float red[4 * 128];
    red[wave * 128 + lane] = s1;
    red[wave * 128 + 64 + lane] = s2;
    __syncthreads();
    if (wave == 0) {
        float a = red[lane] + red[128 + lane] + red[256 + lane] + red[384 + lane];
        atomicAdd(&stats[lane], a);
    } else if (wave == 1) {
        float a = red[64 + lane] + red[192 + lane] + red[320 + lane] + red[448 + lane];
        atomicAdd(&stats[64 + lane], a);
    }
}

// ---------------- batchnorm (batch stats) + relu ----------------
__global__ void bn_relu_k(const float* __restrict__ Y, const float* __restrict__ stats,
                          const float* __restrict__ g, const float* __restrict__ be,
                          float* __restrict__ H) {
    int i = blockIdx.x * blockDim.x + threadIdx.x;
    if (i >= NN * 64) return;
    int j = i & 63;
    const float invN = 1.f / (float)NN;
    float m = stats[j] * invN;
    float v = stats[64 + j] * invN - m * m;
    float r = rsqrtf(v + BN_EPS);
    float val = fmaf(g[j] * r, Y[i] - m, be[j]);
    H[i] = val > 0.f ? val : 0.f;
}

// ---------------- APPNP iteration: Y = 0.9*prop(X) + 0.1*H0 ----------------
__global__ void appnp_k(const float* __restrict__ X, const float* __restrict__ H0,
                        const int* __restrict__ offs, const int* __restrict__ csrc,
                        const float* __restrict__ cw, const float* __restrict__ dinv,
                        float* __restrict__ Y) {
    int lane = threadIdx.x & 63;
    int wid = blockIdx.x * (blockDim.x >> 6) + (threadIdx.x >> 6);
    if (wid >= NN) return;
    int n = wid;
    float dn = dinv[n];
    float acc = dn * dn * X[(size_t)n * 64 + lane];
    int e0 = offs[n], e1 = offs[n + 1];
    for (int e = e0; e < e1; ++e)
        acc = fmaf(cw[e], X[(size_t)csrc[e] * 64 + lane], acc);
    Y[(size_t)n * 64 + lane] = fmaf(0.9f, acc, 0.1f * H0[(size_t)n * 64 + lane]);
}

// ---------------- FC + log_softmax ----------------
__global__ void final_k(const float* __restrict__ H, const float* __restrict__ Wfc,
                        const float* __restrict__ bfc, float* __restrict__ out) {
    __shared__ float Ws[64 * 64];
    for (int i = threadIdx.x; i < 64 * 64; i += blockDim.x) Ws[i] = Wfc[i];
    __syncthreads();
    int lane = threadIdx.x & 63;
    int wid = blockIdx.x * (blockDim.x >> 6) + (threadIdx.x >> 6);
    int nw = gridDim.x * (blockDim.x >> 6);
    for (int n = wid; n < NN; n += nw) {
        float xv = H[(size_t)n * 64 + lane];
        float acc = bfc[lane];
#pragma unroll
        for (int j = 0; j < 64; ++j)
            acc = fmaf(__shfl(xv, j, 64), Ws[j * 64 + lane], acc);
        float m = acc;
#pragma unroll
        for (int d = 32; d; d >>= 1) m = fmaxf(m, __shfl_xor(m, d, 64));
        float ex = expf(acc - m);
        float s = ex;
#pragma unroll
        for (int d = 32; d; d >>= 1) s += __shfl_xor(s, d, 64);
        out[(size_t)n * 64 + lane] = acc - m - logf(s);
    }
}

// ---------------- host launch ----------------

static inline char* alignup(char* p, size_t a) {
    return (char*)(((uintptr_t)p + a - 1) & ~(uintptr_t)(a - 1));
}

extern "C" void kernel_launch(void* const* d_in, const int* in_sizes, int n_in,
                              void* d_out, int out_size, void* d_ws, size_t ws_size,
                              hipStream_t stream) {
    const float* x   = (const float*)d_in[0];
    const int*   ei  = (const int*)d_in[1];       // [2, NE] row-major
    const float* W1  = (const float*)d_in[2];
    const float* b1  = (const float*)d_in[3];
    const float* W2  = (const float*)d_in[4];
    const float* b2  = (const float*)d_in[5];
    const float* Wx  = (const float*)d_in[6];     // [2,64,64]
    const float* bx  = (const float*)d_in[7];     // [2,64]
    const float* g1  = (const float*)d_in[8];
    const float* be1 = (const float*)d_in[9];
    const float* g2  = (const float*)d_in[10];
    const float* be2 = (const float*)d_in[11];
    const float* g3  = (const float*)d_in[12];
    const float* be3 = (const float*)d_in[13];
    const float* Wfc = (const float*)d_in[14];
    const float* bfc = (const float*)d_in[15];
    float* out = (float*)d_out;

    const int* srcA = ei;
    const int* dstA = ei + NE;

    // workspace carve
    char* p = (char*)d_ws;
    int*   deg    = (int*)p;   p += NN * 4;
    int*   cursor = (int*)p;   p += NN * 4;
    float* stats  = (float*)p; p += 512 * 4;     // 4 layers x (sum64 | sumsq64)
    size_t zbytes = (size_t)(p - (char*)d_ws);
    p = alignup(p, 512);
    int*   offs = (int*)p;     p += (NN + 4) * 4; p = alignup(p, 512);
    float* dinv = (float*)p;   p += NN * 4;       p = alignup(p, 512);
    int*   csrc = (int*)p;     p += NE * 4;       p = alignup(p, 512);
    float* cw   = (float*)p;   p += NE * 4;       p = alignup(p, 512);
    float* tmp  = (float*)p;   p += (size_t)NN * 64 * 4; p = alignup(p, 512);
    float* pb   = (float*)p;   p += (size_t)NN * 64 * 4; p = alignup(p, 512);
    float* hb   = (float*)p;   p += (size_t)NN * 64 * 4;

    hipMemsetAsync(d_ws, 0, zbytes, stream);

    // graph prep
    count_k<<<(NE + 255) / 256, 256, 0, stream>>>(dstA, deg);
    dinv_k<<<(NN + 255) / 256, 256, 0, stream>>>(deg, dinv);
    scan_k<<<1, 1024, 0, stream>>>(deg, offs);
    scatter_k<<<(NE + 255) / 256, 256, 0, stream>>>(srcA, dstA, offs, cursor, dinv, csrc, cw);

    // layer 1: x@W1 -> prop+b1 -> bn(g1,be1)+relu
    mm_k<INF_><<<1024, 256, 0, stream>>>(x, W1, tmp);
    prop_stats_k<<<2048, 256, 0, stream>>>(tmp, offs, csrc, cw, dinv, b1, pb, stats + 0 * 128);
    bn_relu_k<<<(NN * 64 + 255) / 256, 256, 0, stream>>>(pb, stats + 0 * 128, g1, be1, hb);

    // layer 2
    mm_k<HID><<<1024, 256, 0, stream>>>(hb, W2, tmp);
    prop_stats_k<<<2048, 256, 0, stream>>>(tmp, offs, csrc, cw, dinv, b2, pb, stats + 1 * 128);
    bn_relu_k<<<(NN * 64 + 255) / 256, 256, 0, stream>>>(pb, stats + 1 * 128, g2, be2, hb);

    // extra layers (share g3/be3)
    for (int L = 0; L < 2; ++L) {
        mm_k<HID><<<1024, 256, 0, stream>>>(hb, Wx + (size_t)L * 64 * 64, tmp);
        prop_stats_k<<<2048, 256, 0, stream>>>(tmp, offs, csrc, cw, dinv, bx + (size_t)L * 64,
                                               pb, stats + (2 + L) * 128);
        bn_relu_k<<<(NN * 64 + 255) / 256, 256, 0, stream>>>(pb, stats + (2 + L) * 128, g3, be3, hb);
    }

    // APPNP: h0 = hb; ping-pong pb/tmp (10 iters -> ends in tmp)
    const float* h0 = hb;
    const float* cur = hb;
    float* bufs[2] = { pb, tmp };
    for (int it = 0; it < 10; ++it) {
        float* o = bufs[it & 1];
        appnp_k<<<(NN + 3) / 4, 256, 0, stream>>>(cur, h0, offs, csrc, cw, dinv, o);
        cur = o;
    }

    final_k<<<2048, 256, 0, stream>>>(cur, Wfc, bfc, out);
}

// Round 2
// 1663.076 us; speedup vs baseline: 1.1966x; 1.1966x over previous
//
#include <hip/hip_runtime.h>
#include <cstdint>
#include <cstddef>

#define NN 50000
#define NE 800000
#define HID 64
#define INF_ 128
#define BN_EPS 1e-5f

// ---------------- graph prep ----------------

__global__ void count_k(const int* __restrict__ dst, int* __restrict__ cnt) {
    int e = blockIdx.x * blockDim.x + threadIdx.x;
    if (e < NE) atomicAdd(&cnt[dst[e]], 1);
}

__global__ void dinv_k(const int* __restrict__ cnt, float* __restrict__ dinv) {
    int n = blockIdx.x * blockDim.x + threadIdx.x;
    if (n < NN) dinv[n] = rsqrtf((float)(cnt[n] + 1));   // +1 self-loop, deg>0 always
}

// single-block exclusive scan of cnt -> offs (offs[NN] = NE)
__global__ void scan_k(const int* __restrict__ cnt, int* __restrict__ offs) {
    __shared__ int part[1024];
    int t = threadIdx.x;
    const int SEG = (NN + 1023) / 1024;   // 49
    int lo = t * SEG;
    int hi = lo + SEG; if (hi > NN) hi = NN; if (lo > NN) lo = NN;
    int s = 0;
    for (int i = lo; i < hi; ++i) s += cnt[i];
    part[t] = s;
    __syncthreads();
    for (int d = 1; d < 1024; d <<= 1) {
        int v = (t >= d) ? part[t - d] : 0;
        __syncthreads();
        part[t] += v;
        __syncthreads();
    }
    int run = (t == 0) ? 0 : part[t - 1];
    for (int i = lo; i < hi; ++i) { offs[i] = run; run += cnt[i]; }
    if (t == 1023) offs[NN] = run;
}

__global__ void scatter_k(const int* __restrict__ src, const int* __restrict__ dst,
                          const int* __restrict__ offs, int* __restrict__ cursor,
                          const float* __restrict__ dinv,
                          int* __restrict__ csrc, float* __restrict__ cw) {
    int e = blockIdx.x * blockDim.x + threadIdx.x;
    if (e < NE) {
        int s = src[e], d = dst[e];
        int pos = offs[d] + atomicAdd(&cursor[d], 1);
        csrc[pos] = s;
        cw[pos] = dinv[s] * dinv[d];
    }
}

// ---------------- dense matmul: Y[N,64] = X[N,K] @ W[K,64] ----------------
// Register-blocked, cache-tiled, NO LDS in inner loop.
// Block = 256 threads -> 64-node x 64-col tile; thread owns 4x4 micro-tile.
template <int K>
__global__ __launch_bounds__(256) void mm_k(const float* __restrict__ X,
                                            const float* __restrict__ W,
                                            float* __restrict__ Y) {
    const int t = threadIdx.x;
    const int n0 = blockIdx.x * 64;
    const int r0 = (t >> 4) << 2;          // 0..60
    const int c0 = (t & 15) << 2;          // 0..60

    // clamp row indices for the tail block (reads valid mem; stores guarded)
    int r[4];
#pragma unroll
    for (int j = 0; j < 4; ++j) {
        int rr = n0 + r0 + j;
        r[j] = rr < NN ? rr : NN - 1;
    }
    const float4* Xr0 = (const float4*)(X + (size_t)r[0] * K);
    const float4* Xr1 = (const float4*)(X + (size_t)r[1] * K);
    const float4* Xr2 = (const float4*)(X + (size_t)r[2] * K);
    const float4* Xr3 = (const float4*)(X + (size_t)r[3] * K);

    float acc[4][4];
#pragma unroll
    for (int j = 0; j < 4; ++j)
#pragma unroll
        for (int c = 0; c < 4; ++c) acc[j][c] = 0.f;

#pragma unroll 4
    for (int kq = 0; kq < K / 4; ++kq) {
        float4 xv[4];
        xv[0] = Xr0[kq]; xv[1] = Xr1[kq]; xv[2] = Xr2[kq]; xv[3] = Xr3[kq];
        float4 wv[4];
#pragma unroll
        for (int i = 0; i < 4; ++i)
            wv[i] = *(const float4*)(W + (size_t)(kq * 4 + i) * 64 + c0);
#pragma unroll
        for (int j = 0; j < 4; ++j) {
            acc[j][0] = fmaf(xv[j].x, wv[0].x, acc[j][0]);
            acc[j][1] = fmaf(xv[j].x, wv[0].y, acc[j][1]);
            acc[j][2] = fmaf(xv[j].x, wv[0].z, acc[j][2]);
            acc[j][3] = fmaf(xv[j].x, wv[0].w, acc[j][3]);
            acc[j][0] = fmaf(xv[j].y, wv[1].x, acc[j][0]);
            acc[j][1] = fmaf(xv[j].y, wv[1].y, acc[j][1]);
            acc[j][2] = fmaf(xv[j].y, wv[1].z, acc[j][2]);
            acc[j][3] = fmaf(xv[j].y, wv[1].w, acc[j][3]);
            acc[j][0] = fmaf(xv[j].z, wv[2].x, acc[j][0]);
            acc[j][1] = fmaf(xv[j].z, wv[2].y, acc[j][1]);
            acc[j][2] = fmaf(xv[j].z, wv[2].z, acc[j][2]);
            acc[j][3] = fmaf(xv[j].z, wv[2].w, acc[j][3]);
            acc[j][0] = fmaf(xv[j].w, wv[3].x, acc[j][0]);
            acc[j][1] = fmaf(xv[j].w, wv[3].y, acc[j][1]);
            acc[j][2] = fmaf(xv[j].w, wv[3].z, acc[j][2]);
            acc[j][3] = fmaf(xv[j].w, wv[3].w, acc[j][3]);
        }
    }

#pragma unroll
    for (int j = 0; j < 4; ++j) {
        int rr = n0 + r0 + j;
        if (rr < NN) {
            float4 o = make_float4(acc[j][0], acc[j][1], acc[j][2], acc[j][3]);
            *(float4*)(Y + (size_t)rr * 64 + c0) = o;
        }
    }
}

// ---------------- propagate + bias + BN-stat accumulation ----------------
// Y[n] = dinv[n]^2 * X[n] + sum_e w_e X[src_e] + bias ; stats[0:64]+=sum, [64:128]+=sumsq
__global__ void prop_stats_k(const float* __restrict__ X,
                             const int* __restrict__ offs, const int* __restrict__ csrc,
                             const float* __restrict__ cw, const float* __restrict__ dinv,
                             const float* __restrict__ bias,
                             float* __restrict__ Y, float* __restrict__ stats) {
    int lane = threadIdx.x & 63;
    int wave = threadIdx.x >> 6;
    int wid = blockIdx.x * 4 + wave;            // blockDim must be 256
    int nw = gridDim.x * 4;
    float s1 = 0.f, s2 = 0.f;
    for (int n = wid; n < NN; n += nw) {
        float dn = dinv[n];
        float acc = dn * dn * X[(size_t)n * 64 + lane];
        int e0 = offs[n], e1 = offs[n + 1];
        for (int e = e0; e < e1; ++e) {
            int s = csrc[e];
            float w = cw[e];
            acc = fmaf(w, X[(size_t)s * 64 + lane], acc);
        }
        acc += bias[lane];
        Y[(size_t)n * 64 + lane] = acc;
        s1 += acc;
        s2 += acc * acc;
    }
    __shared__ float red[4 * 128];
    red[wave * 128 + lane] = s1;
    red[wave * 128 + 64 + lane] = s2;
    __syncthreads();
    if (wave == 0) {
        float a = red[lane] + red[128 + lane] + red[256 + lane] + red[384 + lane];
        atomicAdd(&stats[lane], a);
    } else if (wave == 1) {
        float a = red[64 + lane] + red[192 + lane] + red[320 + lane] + red[448 + lane];
        atomicAdd(&stats[64 + lane], a);
    }
}

// ---------------- batchnorm (batch stats) + relu ----------------
__global__ void bn_relu_k(const float* __restrict__ Y, const float* __restrict__ stats,
                          const float* __restrict__ g, const float* __restrict__ be,
                          float* __restrict__ H) {
    int i = blockIdx.x * blockDim.x + threadIdx.x;
    if (i >= NN * 64) return;
    int j = i & 63;
    const float invN = 1.f / (float)NN;
    float m = stats[j] * invN;
    float v = stats[64 + j] * invN - m * m;
    float r = rsqrtf(v + BN_EPS);
    float val = fmaf(g[j] * r, Y[i] - m, be[j]);
    H[i] = val > 0.f ? val : 0.f;
}

// ---------------- APPNP iteration: Y = 0.9*prop(X) + 0.1*H0 ----------------
__global__ void appnp_k(const float* __restrict__ X, const float* __restrict__ H0,
                        const int* __restrict__ offs, const int* __restrict__ csrc,
                        const float* __restrict__ cw, const float* __restrict__ dinv,
                        float* __restrict__ Y) {
    int lane = threadIdx.x & 63;
    int wid = blockIdx.x * (blockDim.x >> 6) + (threadIdx.x >> 6);
    if (wid >= NN) return;
    int n = wid;
    float dn = dinv[n];
    float acc = dn * dn * X[(size_t)n * 64 + lane];
    int e0 = offs[n], e1 = offs[n + 1];
    for (int e = e0; e < e1; ++e)
        acc = fmaf(cw[e], X[(size_t)csrc[e] * 64 + lane], acc);
    Y[(size_t)n * 64 + lane] = fmaf(0.9f, acc, 0.1f * H0[(size_t)n * 64 + lane]);
}

// ---------------- FC + log_softmax ----------------
__global__ void final_k(const float* __restrict__ H, const float* __restrict__ Wfc,
                        const float* __restrict__ bfc, float* __restrict__ out) {
    __shared__ float Ws[64 * 64];
    for (int i = threadIdx.x; i < 64 * 64; i += blockDim.x) Ws[i] = Wfc[i];
    __syncthreads();
    int lane = threadIdx.x & 63;
    int wid = blockIdx.x * (blockDim.x >> 6) + (threadIdx.x >> 6);
    int nw = gridDim.x * (blockDim.x >> 6);
    for (int n = wid; n < NN; n += nw) {
        float xv = H[(size_t)n * 64 + lane];
        float acc = bfc[lane];
#pragma unroll
        for (int j = 0; j < 64; ++j)
            acc = fmaf(__shfl(xv, j, 64), Ws[j * 64 + lane], acc);
        float m = acc;
#pragma unroll
        for (int d = 32; d; d >>= 1) m = fmaxf(m, __shfl_xor(m, d, 64));
        float ex = expf(acc - m);
        float s = ex;
#pragma unroll
        for (int d = 32; d; d >>= 1) s += __shfl_xor(s, d, 64);
        out[(size_t)n * 64 + lane] = acc - m - logf(s);
    }
}

// ---------------- host launch ----------------

static inline char* alignup(char* p, size_t a) {
    return (char*)(((uintptr_t)p + a - 1) & ~(uintptr_t)(a - 1));
}

extern "C" void kernel_launch(void* const* d_in, const int* in_sizes, int n_in,
                              void* d_out, int out_size, void* d_ws, size_t ws_size,
                              hipStream_t stream) {
    const float* x   = (const float*)d_in[0];
    const int*   ei  = (const int*)d_in[1];       // [2, NE] row-major
    const float* W1  = (const float*)d_in[2];
    const float* b1  = (const float*)d_in[3];
    const float* W2  = (const float*)d_in[4];
    const float* b2  = (const float*)d_in[5];
    const float* Wx  = (const float*)d_in[6];     // [2,64,64]
    const float* bx  = (const float*)d_in[7];     // [2,64]
    const float* g1  = (const float*)d_in[8];
    const float* be1 = (const float*)d_in[9];
    const float* g2  = (const float*)d_in[10];
    const float* be2 = (const float*)d_in[11];
    const float* g3  = (const float*)d_in[12];
    const float* be3 = (const float*)d_in[13];
    const float* Wfc = (const float*)d_in[14];
    const float* bfc = (const float*)d_in[15];
    float* out = (float*)d_out;

    const int* srcA = ei;
    const int* dstA = ei + NE;

    // workspace carve
    char* p = (char*)d_ws;
    int*   deg    = (int*)p;   p += NN * 4;
    int*   cursor = (int*)p;   p += NN * 4;
    float* stats  = (float*)p; p += 512 * 4;     // 4 layers x (sum64 | sumsq64)
    size_t zbytes = (size_t)(p - (char*)d_ws);
    p = alignup(p, 512);
    int*   offs = (int*)p;     p += (NN + 4) * 4; p = alignup(p, 512);
    float* dinv = (float*)p;   p += NN * 4;       p = alignup(p, 512);
    int*   csrc = (int*)p;     p += NE * 4;       p = alignup(p, 512);
    float* cw   = (float*)p;   p += NE * 4;       p = alignup(p, 512);
    float* tmp  = (float*)p;   p += (size_t)NN * 64 * 4; p = alignup(p, 512);
    float* pb   = (float*)p;   p += (size_t)NN * 64 * 4; p = alignup(p, 512);
    float* hb   = (float*)p;   p += (size_t)NN * 64 * 4;

    hipMemsetAsync(d_ws, 0, zbytes, stream);

    // graph prep
    count_k<<<(NE + 255) / 256, 256, 0, stream>>>(dstA, deg);
    dinv_k<<<(NN + 255) / 256, 256, 0, stream>>>(deg, dinv);
    scan_k<<<1, 1024, 0, stream>>>(deg, offs);
    scatter_k<<<(NE + 255) / 256, 256, 0, stream>>>(srcA, dstA, offs, cursor, dinv, csrc, cw);

    const int MMG = (NN + 63) / 64;   // 782 blocks

    // layer 1: x@W1 -> prop+b1 -> bn(g1,be1)+relu
    mm_k<INF_><<<MMG, 256, 0, stream>>>(x, W1, tmp);
    prop_stats_k<<<2048, 256, 0, stream>>>(tmp, offs, csrc, cw, dinv, b1, pb, stats + 0 * 128);
    bn_relu_k<<<(NN * 64 + 255) / 256, 256, 0, stream>>>(pb, stats + 0 * 128, g1, be1, hb);

    // layer 2
    mm_k<HID><<<MMG, 256, 0, stream>>>(hb, W2, tmp);
    prop_stats_k<<<2048, 256, 0, stream>>>(tmp, offs, csrc, cw, dinv, b2, pb, stats + 1 * 128);
    bn_relu_k<<<(NN * 64 + 255) / 256, 256, 0, stream>>>(pb, stats + 1 * 128, g2, be2, hb);

    // extra layers (share g3/be3)
    for (int L = 0; L < 2; ++L) {
        mm_k<HID><<<MMG, 256, 0, stream>>>(hb, Wx + (size_t)L * 64 * 64, tmp);
        prop_stats_k<<<2048, 256, 0, stream>>>(tmp, offs, csrc, cw, dinv, bx + (size_t)L * 64,
                                               pb, stats + (2 + L) * 128);
        bn_relu_k<<<(NN * 64 + 255) / 256, 256, 0, stream>>>(pb, stats + (2 + L) * 128, g3, be3, hb);
    }

    // APPNP: h0 = hb; ping-pong pb/tmp (10 iters -> ends in tmp)
    const float* h0 = hb;
    const float* cur = hb;
    float* bufs[2] = { pb, tmp };
    for (int it = 0; it < 10; ++it) {
        float* o = bufs[it & 1];
        appnp_k<<<(NN + 3) / 4, 256, 0, stream>>>(cur, h0, offs, csrc, cw, dinv, o);
        cur = o;
    }

    final_k<<<2048, 256, 0, stream>>>(cur, Wfc, bfc, out);
}

// Round 3
// 986.239 us; speedup vs baseline: 2.0179x; 1.6863x over previous
//
#include <hip/hip_runtime.h>
#include <cstdint>
#include <cstddef>

#define NN 50000
#define NE 800000
#define HID 64
#define INF_ 128
#define BN_EPS 1e-5f
// NN % 4 == 0 (50000 = 4*12500) -> node-quad decomposition has no tail
#define NG (NN / 4)

// ---------------- graph prep ----------------

__global__ void count_k(const int* __restrict__ dst, int* __restrict__ cnt) {
    int e = blockIdx.x * blockDim.x + threadIdx.x;
    if (e < NE) atomicAdd(&cnt[dst[e]], 1);
}

__global__ void dinv_k(const int* __restrict__ cnt, float* __restrict__ dinv) {
    int n = blockIdx.x * blockDim.x + threadIdx.x;
    if (n < NN) dinv[n] = rsqrtf((float)(cnt[n] + 1));   // +1 self-loop
}

// single-block exclusive scan of cnt -> offs (offs[NN] = NE)
__global__ void scan_k(const int* __restrict__ cnt, int* __restrict__ offs) {
    __shared__ int part[1024];
    int t = threadIdx.x;
    const int SEG = (NN + 1023) / 1024;   // 49
    int lo = t * SEG;
    int hi = lo + SEG; if (hi > NN) hi = NN; if (lo > NN) lo = NN;
    int s = 0;
    for (int i = lo; i < hi; ++i) s += cnt[i];
    part[t] = s;
    __syncthreads();
    for (int d = 1; d < 1024; d <<= 1) {
        int v = (t >= d) ? part[t - d] : 0;
        __syncthreads();
        part[t] += v;
        __syncthreads();
    }
    int run = (t == 0) ? 0 : part[t - 1];
    for (int i = lo; i < hi; ++i) { offs[i] = run; run += cnt[i]; }
    if (t == 1023) offs[NN] = run;
}

// build CSR edge list as int2 {src, weight-bits}
__global__ void scatter_k(const int* __restrict__ src, const int* __restrict__ dst,
                          const int* __restrict__ offs, int* __restrict__ cursor,
                          const float* __restrict__ dinv,
                          int2* __restrict__ edge2) {
    int e = blockIdx.x * blockDim.x + threadIdx.x;
    if (e < NE) {
        int s = src[e], d = dst[e];
        int pos = offs[d] + atomicAdd(&cursor[d], 1);
        edge2[pos] = make_int2(s, __float_as_int(dinv[s] * dinv[d]));
    }
}

// ---------------- dense matmul: Y[N,64] = X[N,K] @ W[K,64] ----------------
// Register-blocked, NO LDS in inner loop. 64-node x 64-col tile per block.
template <int K>
__global__ __launch_bounds__(256) void mm_k(const float* __restrict__ X,
                                            const float* __restrict__ W,
                                            float* __restrict__ Y) {
    const int t = threadIdx.x;
    const int n0 = blockIdx.x * 64;
    const int r0 = (t >> 4) << 2;
    const int c0 = (t & 15) << 2;

    int r[4];
#pragma unroll
    for (int j = 0; j < 4; ++j) {
        int rr = n0 + r0 + j;
        r[j] = rr < NN ? rr : NN - 1;
    }
    const float4* Xr0 = (const float4*)(X + (size_t)r[0] * K);
    const float4* Xr1 = (const float4*)(X + (size_t)r[1] * K);
    const float4* Xr2 = (const float4*)(X + (size_t)r[2] * K);
    const float4* Xr3 = (const float4*)(X + (size_t)r[3] * K);

    float acc[4][4];
#pragma unroll
    for (int j = 0; j < 4; ++j)
#pragma unroll
        for (int c = 0; c < 4; ++c) acc[j][c] = 0.f;

#pragma unroll 4
    for (int kq = 0; kq < K / 4; ++kq) {
        float4 xv[4];
        xv[0] = Xr0[kq]; xv[1] = Xr1[kq]; xv[2] = Xr2[kq]; xv[3] = Xr3[kq];
        float4 wv[4];
#pragma unroll
        for (int i = 0; i < 4; ++i)
            wv[i] = *(const float4*)(W + (size_t)(kq * 4 + i) * 64 + c0);
#pragma unroll
        for (int j = 0; j < 4; ++j) {
            acc[j][0] = fmaf(xv[j].x, wv[0].x, acc[j][0]);
            acc[j][1] = fmaf(xv[j].x, wv[0].y, acc[j][1]);
            acc[j][2] = fmaf(xv[j].x, wv[0].z, acc[j][2]);
            acc[j][3] = fmaf(xv[j].x, wv[0].w, acc[j][3]);
            acc[j][0] = fmaf(xv[j].y, wv[1].x, acc[j][0]);
            acc[j][1] = fmaf(xv[j].y, wv[1].y, acc[j][1]);
            acc[j][2] = fmaf(xv[j].y, wv[1].z, acc[j][2]);
            acc[j][3] = fmaf(xv[j].y, wv[1].w, acc[j][3]);
            acc[j][0] = fmaf(xv[j].z, wv[2].x, acc[j][0]);
            acc[j][1] = fmaf(xv[j].z, wv[2].y, acc[j][1]);
            acc[j][2] = fmaf(xv[j].z, wv[2].z, acc[j][2]);
            acc[j][3] = fmaf(xv[j].z, wv[2].w, acc[j][3]);
            acc[j][0] = fmaf(xv[j].w, wv[3].x, acc[j][0]);
            acc[j][1] = fmaf(xv[j].w, wv[3].y, acc[j][1]);
            acc[j][2] = fmaf(xv[j].w, wv[3].z, acc[j][2]);
            acc[j][3] = fmaf(xv[j].w, wv[3].w, acc[j][3]);
        }
    }

#pragma unroll
    for (int j = 0; j < 4; ++j) {
        int rr = n0 + r0 + j;
        if (rr < NN)
            *(float4*)(Y + (size_t)rr * 64 + c0) =
                make_float4(acc[j][0], acc[j][1], acc[j][2], acc[j][3]);
    }
}

// ---------------- propagate core: 4 nodes per wave, float4 per lane ----------
// lane layout: slot = lane>>4 (node within quad), fg = lane&15 (feature quad)
__device__ __forceinline__ float4 prop_gather(const float4* __restrict__ X4,
                                              const int2* __restrict__ E,
                                              int e0, int e1, int fg, float4 self) {
    float4 acc = self;
    int e = e0;
    for (; e + 4 <= e1; e += 4) {
        int2 d0 = E[e], d1 = E[e + 1], d2 = E[e + 2], d3 = E[e + 3];
        float4 x0 = X4[(size_t)d0.x * 16 + fg];
        float4 x1 = X4[(size_t)d1.x * 16 + fg];
        float4 x2 = X4[(size_t)d2.x * 16 + fg];
        float4 x3 = X4[(size_t)d3.x * 16 + fg];
        float w0 = __int_as_float(d0.y), w1 = __int_as_float(d1.y);
        float w2 = __int_as_float(d2.y), w3 = __int_as_float(d3.y);
        acc.x = fmaf(w0, x0.x, acc.x); acc.y = fmaf(w0, x0.y, acc.y);
        acc.z = fmaf(w0, x0.z, acc.z); acc.w = fmaf(w0, x0.w, acc.w);
        acc.x = fmaf(w1, x1.x, acc.x); acc.y = fmaf(w1, x1.y, acc.y);
        acc.z = fmaf(w1, x1.z, acc.z); acc.w = fmaf(w1, x1.w, acc.w);
        acc.x = fmaf(w2, x2.x, acc.x); acc.y = fmaf(w2, x2.y, acc.y);
        acc.z = fmaf(w2, x2.z, acc.z); acc.w = fmaf(w2, x2.w, acc.w);
        acc.x = fmaf(w3, x3.x, acc.x); acc.y = fmaf(w3, x3.y, acc.y);
        acc.z = fmaf(w3, x3.z, acc.z); acc.w = fmaf(w3, x3.w, acc.w);
    }
    for (; e < e1; ++e) {
        int2 d0 = E[e];
        float4 x0 = X4[(size_t)d0.x * 16 + fg];
        float w0 = __int_as_float(d0.y);
        acc.x = fmaf(w0, x0.x, acc.x); acc.y = fmaf(w0, x0.y, acc.y);
        acc.z = fmaf(w0, x0.z, acc.z); acc.w = fmaf(w0, x0.w, acc.w);
    }
    return acc;
}

// ---------------- propagate + bias + BN-stat accumulation ----------------
__global__ __launch_bounds__(256) void prop_stats_k(
        const float* __restrict__ X, const int* __restrict__ offs,
        const int2* __restrict__ edge2, const float* __restrict__ dinv,
        const float* __restrict__ bias, float* __restrict__ Y,
        float* __restrict__ stats) {
    const float4* X4 = (const float4*)X;
    const int lane = threadIdx.x & 63;
    const int wave = threadIdx.x >> 6;
    const int slot = lane >> 4;
    const int fg = lane & 15;
    const int wid = blockIdx.x * 4 + wave;
    const int nw = gridDim.x * 4;
    const float4 bias4 = ((const float4*)bias)[fg];

    float4 s1 = make_float4(0, 0, 0, 0), s2 = make_float4(0, 0, 0, 0);

    for (int g = wid; g < NG; g += nw) {
        int n = g * 4 + slot;                 // always < NN (NN%4==0)
        float dn = dinv[n];
        float4 self = X4[(size_t)n * 16 + fg];
        float dd = dn * dn;
        self.x *= dd; self.y *= dd; self.z *= dd; self.w *= dd;
        int e0 = offs[n], e1 = offs[n + 1];
        float4 acc = prop_gather(X4, edge2, e0, e1, fg, self);
        acc.x += bias4.x; acc.y += bias4.y; acc.z += bias4.z; acc.w += bias4.w;
        ((float4*)Y)[(size_t)n * 16 + fg] = acc;
        s1.x += acc.x; s1.y += acc.y; s1.z += acc.z; s1.w += acc.w;
        s2.x = fmaf(acc.x, acc.x, s2.x); s2.y = fmaf(acc.y, acc.y, s2.y);
        s2.z = fmaf(acc.z, acc.z, s2.z); s2.w = fmaf(acc.w, acc.w, s2.w);
    }

    // reduce across the 4 slots (lanes differing in bits 4,5)
#pragma unroll
    for (int m = 16; m <= 32; m <<= 1) {
        s1.x += __shfl_xor(s1.x, m, 64); s1.y += __shfl_xor(s1.y, m, 64);
        s1.z += __shfl_xor(s1.z, m, 64); s1.w += __shfl_xor(s1.w, m, 64);
        s2.x += __shfl_xor(s2.x, m, 64); s2.y += __shfl_xor(s2.y, m, 64);
        s2.z += __shfl_xor(s2.z, m, 64); s2.w += __shfl_xor(s2.w, m, 64);
    }

    __shared__ float red[4][16][8];
    if (lane < 16) {
        red[wave][lane][0] = s1.x; red[wave][lane][1] = s1.y;
        red[wave][lane][2] = s1.z; red[wave][lane][3] = s1.w;
        red[wave][lane][4] = s2.x; red[wave][lane][5] = s2.y;
        red[wave][lane][6] = s2.z; red[wave][lane][7] = s2.w;
    }
    __syncthreads();
    int t = threadIdx.x;
    if (t < 128) {
        int j = t & 63;            // feature index
        int isq = t >> 6;          // 0 = sum, 1 = sumsq
        int fgi = j >> 2, c = (j & 3) + isq * 4;
        float a = red[0][fgi][c] + red[1][fgi][c] + red[2][fgi][c] + red[3][fgi][c];
        atomicAdd(&stats[isq * 64 + j], a);
    }
}

// ---------------- batchnorm (batch stats) + relu ----------------
__global__ void bn_relu_k(const float* __restrict__ Y, const float* __restrict__ stats,
                          const float* __restrict__ g, const float* __restrict__ be,
                          float* __restrict__ H) {
    int i = blockIdx.x * blockDim.x + threadIdx.x;
    if (i >= NN * 64) return;
    int j = i & 63;
    const float invN = 1.f / (float)NN;
    float m = stats[j] * invN;
    float v = stats[64 + j] * invN - m * m;
    float r = rsqrtf(v + BN_EPS);
    float val = fmaf(g[j] * r, Y[i] - m, be[j]);
    H[i] = val > 0.f ? val : 0.f;
}

// ---------------- APPNP iteration: Y = 0.9*prop(X) + 0.1*H0 ----------------
__global__ __launch_bounds__(256) void appnp_k(
        const float* __restrict__ X, const float* __restrict__ H0,
        const int* __restrict__ offs, const int2* __restrict__ edge2,
        const float* __restrict__ dinv, float* __restrict__ Y) {
    const float4* X4 = (const float4*)X;
    const int lane = threadIdx.x & 63;
    const int wave = threadIdx.x >> 6;
    const int slot = lane >> 4;
    const int fg = lane & 15;
    const int wid = blockIdx.x * 4 + wave;
    if (wid >= NG) return;
    int n = wid * 4 + slot;
    float dn = dinv[n];
    float4 self = X4[(size_t)n * 16 + fg];
    float dd = dn * dn;
    self.x *= dd; self.y *= dd; self.z *= dd; self.w *= dd;
    int e0 = offs[n], e1 = offs[n + 1];
    float4 acc = prop_gather(X4, edge2, e0, e1, fg, self);
    float4 h0 = ((const float4*)H0)[(size_t)n * 16 + fg];
    float4 o;
    o.x = fmaf(0.9f, acc.x, 0.1f * h0.x);
    o.y = fmaf(0.9f, acc.y, 0.1f * h0.y);
    o.z = fmaf(0.9f, acc.z, 0.1f * h0.z);
    o.w = fmaf(0.9f, acc.w, 0.1f * h0.w);
    ((float4*)Y)[(size_t)n * 16 + fg] = o;
}

// ---------------- FC + log_softmax (register-blocked mm + 16-lane softmax) ---
__global__ __launch_bounds__(256) void final_k(const float* __restrict__ H,
                                               const float* __restrict__ Wfc,
                                               const float* __restrict__ bfc,
                                               float* __restrict__ out) {
    const int t = threadIdx.x;
    const int n0 = blockIdx.x * 64;
    const int r0 = (t >> 4) << 2;
    const int c0 = (t & 15) << 2;

    int r[4];
#pragma unroll
    for (int j = 0; j < 4; ++j) {
        int rr = n0 + r0 + j;
        r[j] = rr < NN ? rr : NN - 1;
    }
    const float4* Xr0 = (const float4*)(H + (size_t)r[0] * 64);
    const float4* Xr1 = (const float4*)(H + (size_t)r[1] * 64);
    const float4* Xr2 = (const float4*)(H + (size_t)r[2] * 64);
    const float4* Xr3 = (const float4*)(H + (size_t)r[3] * 64);

    float4 bf = *(const float4*)(bfc + c0);
    float acc[4][4];
#pragma unroll
    for (int j = 0; j < 4; ++j) {
        acc[j][0] = bf.x; acc[j][1] = bf.y; acc[j][2] = bf.z; acc[j][3] = bf.w;
    }

#pragma unroll 4
    for (int kq = 0; kq < 16; ++kq) {
        float4 xv[4];
        xv[0] = Xr0[kq]; xv[1] = Xr1[kq]; xv[2] = Xr2[kq]; xv[3] = Xr3[kq];
        float4 wv[4];
#pragma unroll
        for (int i = 0; i < 4; ++i)
            wv[i] = *(const float4*)(Wfc + (size_t)(kq * 4 + i) * 64 + c0);
#pragma unroll
        for (int j = 0; j < 4; ++j) {
            acc[j][0] = fmaf(xv[j].x, wv[0].x, acc[j][0]);
            acc[j][1] = fmaf(xv[j].x, wv[0].y, acc[j][1]);
            acc[j][2] = fmaf(xv[j].x, wv[0].z, acc[j][2]);
            acc[j][3] = fmaf(xv[j].x, wv[0].w, acc[j][3]);
            acc[j][0] = fmaf(xv[j].y, wv[1].x, acc[j][0]);
            acc[j][1] = fmaf(xv[j].y, wv[1].y, acc[j][1]);
            acc[j][2] = fmaf(xv[j].y, wv[1].z, acc[j][2]);
            acc[j][3] = fmaf(xv[j].y, wv[1].w, acc[j][3]);
            acc[j][0] = fmaf(xv[j].z, wv[2].x, acc[j][0]);
            acc[j][1] = fmaf(xv[j].z, wv[2].y, acc[j][1]);
            acc[j][2] = fmaf(xv[j].z, wv[2].z, acc[j][2]);
            acc[j][3] = fmaf(xv[j].z, wv[2].w, acc[j][3]);
            acc[j][0] = fmaf(xv[j].w, wv[3].x, acc[j][0]);
            acc[j][1] = fmaf(xv[j].w, wv[3].y, acc[j][1]);
            acc[j][2] = fmaf(xv[j].w, wv[3].z, acc[j][2]);
            acc[j][3] = fmaf(xv[j].w, wv[3].w, acc[j][3]);
        }
    }

    // per-row log_softmax: reduce across the 16 lanes sharing a row
#pragma unroll
    for (int j = 0; j < 4; ++j) {
        float m = fmaxf(fmaxf(acc[j][0], acc[j][1]), fmaxf(acc[j][2], acc[j][3]));
#pragma unroll
        for (int d = 1; d <= 8; d <<= 1) m = fmaxf(m, __shfl_xor(m, d, 64));
        float s = expf(acc[j][0] - m) + expf(acc[j][1] - m) +
                  expf(acc[j][2] - m) + expf(acc[j][3] - m);
#pragma unroll
        for (int d = 1; d <= 8; d <<= 1) s += __shfl_xor(s, d, 64);
        float lse = m + logf(s);
        int rr = n0 + r0 + j;
        if (rr < NN)
            *(float4*)(out + (size_t)rr * 64 + c0) =
                make_float4(acc[j][0] - lse, acc[j][1] - lse,
                            acc[j][2] - lse, acc[j][3] - lse);
    }
}

// ---------------- host launch ----------------

static inline char* alignup(char* p, size_t a) {
    return (char*)(((uintptr_t)p + a - 1) & ~(uintptr_t)(a - 1));
}

extern "C" void kernel_launch(void* const* d_in, const int* in_sizes, int n_in,
                              void* d_out, int out_size, void* d_ws, size_t ws_size,
                              hipStream_t stream) {
    const float* x   = (const float*)d_in[0];
    const int*   ei  = (const int*)d_in[1];
    const float* W1  = (const float*)d_in[2];
    const float* b1  = (const float*)d_in[3];
    const float* W2  = (const float*)d_in[4];
    const float* b2  = (const float*)d_in[5];
    const float* Wx  = (const float*)d_in[6];
    const float* bx  = (const float*)d_in[7];
    const float* g1  = (const float*)d_in[8];
    const float* be1 = (const float*)d_in[9];
    const float* g2  = (const float*)d_in[10];
    const float* be2 = (const float*)d_in[11];
    const float* g3  = (const float*)d_in[12];
    const float* be3 = (const float*)d_in[13];
    const float* Wfc = (const float*)d_in[14];
    const float* bfc = (const float*)d_in[15];
    float* out = (float*)d_out;

    const int* srcA = ei;
    const int* dstA = ei + NE;

    char* p = (char*)d_ws;
    int*   deg    = (int*)p;   p += NN * 4;
    int*   cursor = (int*)p;   p += NN * 4;
    float* stats  = (float*)p; p += 512 * 4;
    size_t zbytes = (size_t)(p - (char*)d_ws);
    p = alignup(p, 512);
    int*   offs  = (int*)p;    p += (NN + 4) * 4; p = alignup(p, 512);
    float* dinv  = (float*)p;  p += NN * 4;       p = alignup(p, 512);
    int2*  edge2 = (int2*)p;   p += (size_t)NE * 8; p = alignup(p, 512);
    float* tmp   = (float*)p;  p += (size_t)NN * 64 * 4; p = alignup(p, 512);
    float* pb    = (float*)p;  p += (size_t)NN * 64 * 4; p = alignup(p, 512);
    float* hb    = (float*)p;  p += (size_t)NN * 64 * 4;

    hipMemsetAsync(d_ws, 0, zbytes, stream);

    count_k<<<(NE + 255) / 256, 256, 0, stream>>>(dstA, deg);
    dinv_k<<<(NN + 255) / 256, 256, 0, stream>>>(deg, dinv);
    scan_k<<<1, 1024, 0, stream>>>(deg, offs);
    scatter_k<<<(NE + 255) / 256, 256, 0, stream>>>(srcA, dstA, offs, cursor, dinv, edge2);

    const int MMG = (NN + 63) / 64;        // 782
    const int PG  = 2048;                  // prop_stats grid (grid-stride)
    const int AG  = (NG + 3) / 4;          // appnp grid: 3125 blocks, exact cover

    mm_k<INF_><<<MMG, 256, 0, stream>>>(x, W1, tmp);
    prop_stats_k<<<PG, 256, 0, stream>>>(tmp, offs, edge2, dinv, b1, pb, stats + 0 * 128);
    bn_relu_k<<<(NN * 64 + 255) / 256, 256, 0, stream>>>(pb, stats + 0 * 128, g1, be1, hb);

    mm_k<HID><<<MMG, 256, 0, stream>>>(hb, W2, tmp);
    prop_stats_k<<<PG, 256, 0, stream>>>(tmp, offs, edge2, dinv, b2, pb, stats + 1 * 128);
    bn_relu_k<<<(NN * 64 + 255) / 256, 256, 0, stream>>>(pb, stats + 1 * 128, g2, be2, hb);

    for (int L = 0; L < 2; ++L) {
        mm_k<HID><<<MMG, 256, 0, stream>>>(hb, Wx + (size_t)L * 64 * 64, tmp);
        prop_stats_k<<<PG, 256, 0, stream>>>(tmp, offs, edge2, dinv, bx + (size_t)L * 64,
                                             pb, stats + (2 + L) * 128);
        bn_relu_k<<<(NN * 64 + 255) / 256, 256, 0, stream>>>(pb, stats + (2 + L) * 128, g3, be3, hb);
    }

    const float* h0 = hb;
    const float* cur = hb;
    float* bufs[2] = { pb, tmp };
    for (int it = 0; it < 10; ++it) {
        float* o = bufs[it & 1];
        appnp_k<<<AG, 256, 0, stream>>>(cur, h0, offs, edge2, dinv, o);
        cur = o;
    }

    final_k<<<MMG, 256, 0, stream>>>(cur, Wfc, bfc, out);
}

// Round 4
// 840.124 us; speedup vs baseline: 2.3688x; 1.1739x over previous
//
#include <hip/hip_runtime.h>
#include <hip/hip_fp16.h>
#include <cstdint>
#include <cstddef>

#define NN 50000
#define NE 800000
#define HID 64
#define INF_ 128
#define BN_EPS 1e-5f
#define NG (NN / 4)          // 12500 node-quads (NN % 4 == 0)
#define SCAN_B 196           // ceil(50000/256)

// ---------------- fp16 pack/unpack (8B = 4 features) ----------------
__device__ __forceinline__ float4 h8_to_f4(float2 raw) {
    union { float f; __half2 h; } ua, ub;
    ua.f = raw.x; ub.f = raw.y;
    float2 fa = __half22float2(ua.h), fb = __half22float2(ub.h);
    return make_float4(fa.x, fa.y, fb.x, fb.y);
}
__device__ __forceinline__ float2 f4_to_h8(float4 v) {
    union { float f; __half2 h; } ua, ub;
    ua.h = __float22half2_rn(make_float2(v.x, v.y));
    ub.h = __float22half2_rn(make_float2(v.z, v.w));
    return make_float2(ua.f, ub.f);
}

// ---------------- graph prep ----------------

__global__ void count_k(const int* __restrict__ dst, int* __restrict__ cnt) {
    int e = blockIdx.x * blockDim.x + threadIdx.x;
    if (e < NE) atomicAdd(&cnt[dst[e]], 1);
}

__global__ void dinv_k(const int* __restrict__ cnt, float* __restrict__ dinv) {
    int n = blockIdx.x * blockDim.x + threadIdx.x;
    if (n < NN) dinv[n] = rsqrtf((float)(cnt[n] + 1));   // +1 self-loop
}

// parallel scan of PADDED degrees ((deg+3)&~3) -> offs; 3 kernels
__global__ void scan1_k(const int* __restrict__ cnt, int* __restrict__ offs,
                        int* __restrict__ bsum) {
    __shared__ int sh[256];
    int t = threadIdx.x, i = blockIdx.x * 256 + t;
    int v = (i < NN) ? ((cnt[i] + 3) & ~3) : 0;
    sh[t] = v;
    __syncthreads();
    for (int d = 1; d < 256; d <<= 1) {
        int u = (t >= d) ? sh[t - d] : 0;
        __syncthreads();
        sh[t] += u;
        __syncthreads();
    }
    if (i < NN) offs[i] = sh[t] - v;          // exclusive within block
    if (t == 255) bsum[blockIdx.x] = sh[255];
}

__global__ void scan2_k(const int* __restrict__ bsum, int* __restrict__ bpre,
                        int* __restrict__ offs) {
    __shared__ int sh[256];
    int t = threadIdx.x;
    int v = (t < SCAN_B) ? bsum[t] : 0;
    sh[t] = v;
    __syncthreads();
    for (int d = 1; d < 256; d <<= 1) {
        int u = (t >= d) ? sh[t - d] : 0;
        __syncthreads();
        sh[t] += u;
        __syncthreads();
    }
    bpre[t] = sh[t] - v;
    if (t == 255) offs[NN] = sh[255];         // total padded edge count
}

__global__ void scan3_k(int* __restrict__ offs, const int* __restrict__ bpre) {
    int i = blockIdx.x * blockDim.x + threadIdx.x;
    if (i < NN) offs[i] += bpre[i >> 8];
}

// fill pad slots with zero-weight edges -> gather loop has no remainder
__global__ void pad_k(const int* __restrict__ cnt, const int* __restrict__ offs,
                      int2* __restrict__ edge2) {
    int n = blockIdx.x * blockDim.x + threadIdx.x;
    if (n >= NN) return;
    int e = offs[n] + cnt[n], e1 = offs[n + 1];
    for (; e < e1; ++e) edge2[e] = make_int2(0, 0);   // w = 0.0f
}

__global__ void scatter_k(const int* __restrict__ src, const int* __restrict__ dst,
                          const int* __restrict__ offs, int* __restrict__ cursor,
                          const float* __restrict__ dinv,
                          int2* __restrict__ edge2) {
    int e = blockIdx.x * blockDim.x + threadIdx.x;
    if (e < NE) {
        int s = src[e], d = dst[e];
        int pos = offs[d] + atomicAdd(&cursor[d], 1);
        edge2[pos] = make_int2(s, __float_as_int(dinv[s] * dinv[d]));
    }
}

// ---------------- dense matmul: Y[N,64] = X[N,K] @ W[K,64], fp16 out --------
// HIN: X is fp16 (8B/lane-loads), else fp32. Register-blocked, no LDS.
template <int K, bool HIN>
__global__ __launch_bounds__(256) void mm_k(const void* __restrict__ Xv,
                                            const float* __restrict__ W,
                                            float2* __restrict__ Y) {
    const int t = threadIdx.x;
    const int n0 = blockIdx.x * 64;
    const int r0 = (t >> 4) << 2;
    const int c0 = (t & 15) << 2;

    int r[4];
#pragma unroll
    for (int j = 0; j < 4; ++j) {
        int rr = n0 + r0 + j;
        r[j] = rr < NN ? rr : NN - 1;
    }
    const float4* Xr4[4];
    const float2* Xr2[4];
#pragma unroll
    for (int j = 0; j < 4; ++j) {
        if (HIN) Xr2[j] = (const float2*)Xv + (size_t)r[j] * (K / 4);
        else     Xr4[j] = (const float4*)Xv + (size_t)r[j] * (K / 4);
    }

    float acc[4][4];
#pragma unroll
    for (int j = 0; j < 4; ++j)
#pragma unroll
        for (int c = 0; c < 4; ++c) acc[j][c] = 0.f;

#pragma unroll 4
    for (int kq = 0; kq < K / 4; ++kq) {
        float4 xv[4];
#pragma unroll
        for (int j = 0; j < 4; ++j)
            xv[j] = HIN ? h8_to_f4(Xr2[j][kq]) : Xr4[j][kq];
        float4 wv[4];
#pragma unroll
        for (int i = 0; i < 4; ++i)
            wv[i] = *(const float4*)(W + (size_t)(kq * 4 + i) * 64 + c0);
#pragma unroll
        for (int j = 0; j < 4; ++j) {
            acc[j][0] = fmaf(xv[j].x, wv[0].x, acc[j][0]);
            acc[j][1] = fmaf(xv[j].x, wv[0].y, acc[j][1]);
            acc[j][2] = fmaf(xv[j].x, wv[0].z, acc[j][2]);
            acc[j][3] = fmaf(xv[j].x, wv[0].w, acc[j][3]);
            acc[j][0] = fmaf(xv[j].y, wv[1].x, acc[j][0]);
            acc[j][1] = fmaf(xv[j].y, wv[1].y, acc[j][1]);
            acc[j][2] = fmaf(xv[j].y, wv[1].z, acc[j][2]);
            acc[j][3] = fmaf(xv[j].y, wv[1].w, acc[j][3]);
            acc[j][0] = fmaf(xv[j].z, wv[2].x, acc[j][0]);
            acc[j][1] = fmaf(xv[j].z, wv[2].y, acc[j][1]);
            acc[j][2] = fmaf(xv[j].z, wv[2].z, acc[j][2]);
            acc[j][3] = fmaf(xv[j].z, wv[2].w, acc[j][3]);
            acc[j][0] = fmaf(xv[j].w, wv[3].x, acc[j][0]);
            acc[j][1] = fmaf(xv[j].w, wv[3].y, acc[j][1]);
            acc[j][2] = fmaf(xv[j].w, wv[3].z, acc[j][2]);
            acc[j][3] = fmaf(xv[j].w, wv[3].w, acc[j][3]);
        }
    }

#pragma unroll
    for (int j = 0; j < 4; ++j) {
        int rr = n0 + r0 + j;
        if (rr < NN)
            Y[(size_t)rr * 16 + (t & 15)] =
                f4_to_h8(make_float4(acc[j][0], acc[j][1], acc[j][2], acc[j][3]));
    }
}

// ---------------- propagate core: fp16 gather, 4 nodes/wave, no remainder ---
__device__ __forceinline__ float4 prop_gather(const float2* __restrict__ X2,
                                              const int2* __restrict__ E,
                                              int e0, int e1, int fg, float4 acc) {
    for (int e = e0; e < e1; e += 4) {   // e1-e0 is a multiple of 4 (padded)
        int2 d0 = E[e], d1 = E[e + 1], d2 = E[e + 2], d3 = E[e + 3];
        float4 x0 = h8_to_f4(X2[(size_t)d0.x * 16 + fg]);
        float4 x1 = h8_to_f4(X2[(size_t)d1.x * 16 + fg]);
        float4 x2 = h8_to_f4(X2[(size_t)d2.x * 16 + fg]);
        float4 x3 = h8_to_f4(X2[(size_t)d3.x * 16 + fg]);
        float w0 = __int_as_float(d0.y), w1 = __int_as_float(d1.y);
        float w2 = __int_as_float(d2.y), w3 = __int_as_float(d3.y);
        acc.x = fmaf(w0, x0.x, acc.x); acc.y = fmaf(w0, x0.y, acc.y);
        acc.z = fmaf(w0, x0.z, acc.z); acc.w = fmaf(w0, x0.w, acc.w);
        acc.x = fmaf(w1, x1.x, acc.x); acc.y = fmaf(w1, x1.y, acc.y);
        acc.z = fmaf(w1, x1.z, acc.z); acc.w = fmaf(w1, x1.w, acc.w);
        acc.x = fmaf(w2, x2.x, acc.x); acc.y = fmaf(w2, x2.y, acc.y);
        acc.z = fmaf(w2, x2.z, acc.z); acc.w = fmaf(w2, x2.w, acc.w);
        acc.x = fmaf(w3, x3.x, acc.x); acc.y = fmaf(w3, x3.y, acc.y);
        acc.z = fmaf(w3, x3.z, acc.z); acc.w = fmaf(w3, x3.w, acc.w);
    }
    return acc;
}

// ---------------- propagate + bias + BN-stat accumulation (fp16 in, fp32 out)
__global__ __launch_bounds__(256) void prop_stats_k(
        const float2* __restrict__ X2, const int* __restrict__ offs,
        const int2* __restrict__ edge2, const float* __restrict__ dinv,
        const float* __restrict__ bias, float4* __restrict__ Y4,
        float* __restrict__ stats) {
    const int lane = threadIdx.x & 63;
    const int wave = threadIdx.x >> 6;
    const int slot = lane >> 4;
    const int fg = lane & 15;
    const int wid = blockIdx.x * 4 + wave;
    const int nw = gridDim.x * 4;
    const float4 bias4 = ((const float4*)bias)[fg];

    float4 s1 = make_float4(0, 0, 0, 0), s2 = make_float4(0, 0, 0, 0);

    for (int g = wid; g < NG; g += nw) {
        int n = g * 4 + slot;
        float dn = dinv[n];
        float4 self = h8_to_f4(X2[(size_t)n * 16 + fg]);
        float dd = dn * dn;
        self.x *= dd; self.y *= dd; self.z *= dd; self.w *= dd;
        int e0 = offs[n], e1 = offs[n + 1];
        float4 acc = prop_gather(X2, edge2, e0, e1, fg, self);
        acc.x += bias4.x; acc.y += bias4.y; acc.z += bias4.z; acc.w += bias4.w;
        Y4[(size_t)n * 16 + fg] = acc;
        s1.x += acc.x; s1.y += acc.y; s1.z += acc.z; s1.w += acc.w;
        s2.x = fmaf(acc.x, acc.x, s2.x); s2.y = fmaf(acc.y, acc.y, s2.y);
        s2.z = fmaf(acc.z, acc.z, s2.z); s2.w = fmaf(acc.w, acc.w, s2.w);
    }

#pragma unroll
    for (int m = 16; m <= 32; m <<= 1) {
        s1.x += __shfl_xor(s1.x, m, 64); s1.y += __shfl_xor(s1.y, m, 64);
        s1.z += __shfl_xor(s1.z, m, 64); s1.w += __shfl_xor(s1.w, m, 64);
        s2.x += __shfl_xor(s2.x, m, 64); s2.y += __shfl_xor(s2.y, m, 64);
        s2.z += __shfl_xor(s2.z, m, 64); s2.w += __shfl_xor(s2.w, m, 64);
    }

    __shared__ float red[4][16][8];
    if (lane < 16) {
        red[wave][lane][0] = s1.x; red[wave][lane][1] = s1.y;
        red[wave][lane][2] = s1.z; red[wave][lane][3] = s1.w;
        red[wave][lane][4] = s2.x; red[wave][lane][5] = s2.y;
        red[wave][lane][6] = s2.z; red[wave][lane][7] = s2.w;
    }
    __syncthreads();
    int t = threadIdx.x;
    if (t < 128) {
        int j = t & 63;
        int isq = t >> 6;
        int fgi = j >> 2, c = (j & 3) + isq * 4;
        float a = red[0][fgi][c] + red[1][fgi][c] + red[2][fgi][c] + red[3][fgi][c];
        atomicAdd(&stats[isq * 64 + j], a);
    }
}

// ---------------- batchnorm + relu: fp32 in -> fp16 out ----------------
__global__ void bn_relu_k(const float4* __restrict__ Y4, const float* __restrict__ stats,
                          const float* __restrict__ g, const float* __restrict__ be,
                          float2* __restrict__ H2) {
    int i = blockIdx.x * blockDim.x + threadIdx.x;
    if (i >= NN * 16) return;
    int fg = i & 15;
    const float invN = 1.f / (float)NN;
    float4 sm = ((const float4*)stats)[fg];
    float4 sq = ((const float4*)stats)[16 + fg];
    float4 gv = ((const float4*)g)[fg];
    float4 bv = ((const float4*)be)[fg];
    float4 y = Y4[i];
    float4 o;
    {
        float m = sm.x * invN, v = sq.x * invN - m * m;
        o.x = fmaf(gv.x * rsqrtf(v + BN_EPS), y.x - m, bv.x);
        m = sm.y * invN; v = sq.y * invN - m * m;
        o.y = fmaf(gv.y * rsqrtf(v + BN_EPS), y.y - m, bv.y);
        m = sm.z * invN; v = sq.z * invN - m * m;
        o.z = fmaf(gv.z * rsqrtf(v + BN_EPS), y.z - m, bv.z);
        m = sm.w * invN; v = sq.w * invN - m * m;
        o.w = fmaf(gv.w * rsqrtf(v + BN_EPS), y.w - m, bv.w);
    }
    o.x = o.x > 0.f ? o.x : 0.f;
    o.y = o.y > 0.f ? o.y : 0.f;
    o.z = o.z > 0.f ? o.z : 0.f;
    o.w = o.w > 0.f ? o.w : 0.f;
    H2[i] = f4_to_h8(o);
}

// ---------------- APPNP iteration (all fp16 buffers) ----------------
__global__ __launch_bounds__(256) void appnp_k(
        const float2* __restrict__ X2, const float2* __restrict__ H02,
        const int* __restrict__ offs, const int2* __restrict__ edge2,
        const float* __restrict__ dinv, float2* __restrict__ Y2) {
    const int lane = threadIdx.x & 63;
    const int wave = threadIdx.x >> 6;
    const int slot = lane >> 4;
    const int fg = lane & 15;
    const int wid = blockIdx.x * 4 + wave;
    if (wid >= NG) return;
    int n = wid * 4 + slot;
    float dn = dinv[n];
    float4 self = h8_to_f4(X2[(size_t)n * 16 + fg]);
    float dd = dn * dn;
    self.x *= dd; self.y *= dd; self.z *= dd; self.w *= dd;
    int e0 = offs[n], e1 = offs[n + 1];
    float4 acc = prop_gather(X2, edge2, e0, e1, fg, self);
    float4 h0 = h8_to_f4(H02[(size_t)n * 16 + fg]);
    float4 o;
    o.x = fmaf(0.9f, acc.x, 0.1f * h0.x);
    o.y = fmaf(0.9f, acc.y, 0.1f * h0.y);
    o.z = fmaf(0.9f, acc.z, 0.1f * h0.z);
    o.w = fmaf(0.9f, acc.w, 0.1f * h0.w);
    Y2[(size_t)n * 16 + fg] = o.x == o.x ? f4_to_h8(o) : f4_to_h8(o); // plain store
}

// ---------------- FC + log_softmax (fp16 in, fp32 out) ----------------
__global__ __launch_bounds__(256) void final_k(const float2* __restrict__ H2,
                                               const float* __restrict__ Wfc,
                                               const float* __restrict__ bfc,
                                               float* __restrict__ out) {
    const int t = threadIdx.x;
    const int n0 = blockIdx.x * 64;
    const int r0 = (t >> 4) << 2;
    const int c0 = (t & 15) << 2;

    int r[4];
#pragma unroll
    for (int j = 0; j < 4; ++j) {
        int rr = n0 + r0 + j;
        r[j] = rr < NN ? rr : NN - 1;
    }
    const float2* Xr[4];
#pragma unroll
    for (int j = 0; j < 4; ++j) Xr[j] = H2 + (size_t)r[j] * 16;

    float4 bf = *(const float4*)(bfc + c0);
    float acc[4][4];
#pragma unroll
    for (int j = 0; j < 4; ++j) {
        acc[j][0] = bf.x; acc[j][1] = bf.y; acc[j][2] = bf.z; acc[j][3] = bf.w;
    }

#pragma unroll 4
    for (int kq = 0; kq < 16; ++kq) {
        float4 xv[4];
#pragma unroll
        for (int j = 0; j < 4; ++j) xv[j] = h8_to_f4(Xr[j][kq]);
        float4 wv[4];
#pragma unroll
        for (int i = 0; i < 4; ++i)
            wv[i] = *(const float4*)(Wfc + (size_t)(kq * 4 + i) * 64 + c0);
#pragma unroll
        for (int j = 0; j < 4; ++j) {
            acc[j][0] = fmaf(xv[j].x, wv[0].x, acc[j][0]);
            acc[j][1] = fmaf(xv[j].x, wv[0].y, acc[j][1]);
            acc[j][2] = fmaf(xv[j].x, wv[0].z, acc[j][2]);
            acc[j][3] = fmaf(xv[j].x, wv[0].w, acc[j][3]);
            acc[j][0] = fmaf(xv[j].y, wv[1].x, acc[j][0]);
            acc[j][1] = fmaf(xv[j].y, wv[1].y, acc[j][1]);
            acc[j][2] = fmaf(xv[j].y, wv[1].z, acc[j][2]);
            acc[j][3] = fmaf(xv[j].y, wv[1].w, acc[j][3]);
            acc[j][0] = fmaf(xv[j].z, wv[2].x, acc[j][0]);
            acc[j][1] = fmaf(xv[j].z, wv[2].y, acc[j][1]);
            acc[j][2] = fmaf(xv[j].z, wv[2].z, acc[j][2]);
            acc[j][3] = fmaf(xv[j].z, wv[2].w, acc[j][3]);
            acc[j][0] = fmaf(xv[j].w, wv[3].x, acc[j][0]);
            acc[j][1] = fmaf(xv[j].w, wv[3].y, acc[j][1]);
            acc[j][2] = fmaf(xv[j].w, wv[3].z, acc[j][2]);
            acc[j][3] = fmaf(xv[j].w, wv[3].w, acc[j][3]);
        }
    }

#pragma unroll
    for (int j = 0; j < 4; ++j) {
        float m = fmaxf(fmaxf(acc[j][0], acc[j][1]), fmaxf(acc[j][2], acc[j][3]));
#pragma unroll
        for (int d = 1; d <= 8; d <<= 1) m = fmaxf(m, __shfl_xor(m, d, 64));
        float s = expf(acc[j][0] - m) + expf(acc[j][1] - m) +
                  expf(acc[j][2] - m) + expf(acc[j][3] - m);
#pragma unroll
        for (int d = 1; d <= 8; d <<= 1) s += __shfl_xor(s, d, 64);
        float lse = m + logf(s);
        int rr = n0 + r0 + j;
        if (rr < NN)
            *(float4*)(out + (size_t)rr * 64 + c0) =
                make_float4(acc[j][0] - lse, acc[j][1] - lse,
                            acc[j][2] - lse, acc[j][3] - lse);
    }
}

// ---------------- host launch ----------------

static inline char* alignup(char* p, size_t a) {
    return (char*)(((uintptr_t)p + a - 1) & ~(uintptr_t)(a - 1));
}

extern "C" void kernel_launch(void* const* d_in, const int* in_sizes, int n_in,
                              void* d_out, int out_size, void* d_ws, size_t ws_size,
                              hipStream_t stream) {
    const float* x   = (const float*)d_in[0];
    const int*   ei  = (const int*)d_in[1];
    const float* W1  = (const float*)d_in[2];
    const float* b1  = (const float*)d_in[3];
    const float* W2  = (const float*)d_in[4];
    const float* b2  = (const float*)d_in[5];
    const float* Wx  = (const float*)d_in[6];
    const float* bx  = (const float*)d_in[7];
    const float* g1  = (const float*)d_in[8];
    const float* be1 = (const float*)d_in[9];
    const float* g2  = (const float*)d_in[10];
    const float* be2 = (const float*)d_in[11];
    const float* g3  = (const float*)d_in[12];
    const float* be3 = (const float*)d_in[13];
    const float* Wfc = (const float*)d_in[14];
    const float* bfc = (const float*)d_in[15];
    float* out = (float*)d_out;

    const int* srcA = ei;
    const int* dstA = ei + NE;

    char* p = (char*)d_ws;
    int*   deg    = (int*)p;   p += NN * 4;
    int*   cursor = (int*)p;   p += NN * 4;
    float* stats  = (float*)p; p += 512 * 4;
    size_t zbytes = (size_t)(p - (char*)d_ws);
    p = alignup(p, 512);
    int*   offs  = (int*)p;    p += (NN + 4) * 4;   p = alignup(p, 512);
    float* dinv  = (float*)p;  p += NN * 4;         p = alignup(p, 512);
    int*   bsum  = (int*)p;    p += 256 * 4;
    int*   bpre  = (int*)p;    p += 256 * 4;        p = alignup(p, 512);
    int2*  edge2 = (int2*)p;   p += ((size_t)NE + 3 * NN + 256) * 8; p = alignup(p, 512);
    float2* tmpH = (float2*)p; p += (size_t)NN * 64 * 2; p = alignup(p, 512);
    float2* hbH  = (float2*)p; p += (size_t)NN * 64 * 2; p = alignup(p, 512);
    float2* apH  = (float2*)p; p += (size_t)NN * 64 * 2; p = alignup(p, 512);
    float4* pbF  = (float4*)p; p += (size_t)NN * 64 * 4;

    hipMemsetAsync(d_ws, 0, zbytes, stream);

    // graph prep: count -> dinv -> padded scan (3k) -> pad -> scatter
    count_k<<<(NE + 255) / 256, 256, 0, stream>>>(dstA, deg);
    dinv_k<<<(NN + 255) / 256, 256, 0, stream>>>(deg, dinv);
    scan1_k<<<SCAN_B, 256, 0, stream>>>(deg, offs, bsum);
    scan2_k<<<1, 256, 0, stream>>>(bsum, bpre, offs);
    scan3_k<<<(NN + 255) / 256, 256, 0, stream>>>(offs, bpre);
    pad_k<<<(NN + 255) / 256, 256, 0, stream>>>(deg, offs, edge2);
    scatter_k<<<(NE + 255) / 256, 256, 0, stream>>>(srcA, dstA, offs, cursor, dinv, edge2);

    const int MMG = (NN + 63) / 64;        // 782
    const int PG  = 3125;                  // NG/4: one quad per wave
    const int AG  = 3125;
    const int BNG = (NN * 16 + 255) / 256;

    mm_k<INF_, false><<<MMG, 256, 0, stream>>>(x, W1, tmpH);
    prop_stats_k<<<PG, 256, 0, stream>>>(tmpH, offs, edge2, dinv, b1, pbF, stats + 0 * 128);
    bn_relu_k<<<BNG, 256, 0, stream>>>(pbF, stats + 0 * 128, g1, be1, hbH);

    mm_k<HID, true><<<MMG, 256, 0, stream>>>(hbH, W2, tmpH);
    prop_stats_k<<<PG, 256, 0, stream>>>(tmpH, offs, edge2, dinv, b2, pbF, stats + 1 * 128);
    bn_relu_k<<<BNG, 256, 0, stream>>>(pbF, stats + 1 * 128, g2, be2, hbH);

    for (int L = 0; L < 2; ++L) {
        mm_k<HID, true><<<MMG, 256, 0, stream>>>(hbH, Wx + (size_t)L * 64 * 64, tmpH);
        prop_stats_k<<<PG, 256, 0, stream>>>(tmpH, offs, edge2, dinv, bx + (size_t)L * 64,
                                             pbF, stats + (2 + L) * 128);
        bn_relu_k<<<BNG, 256, 0, stream>>>(pbF, stats + (2 + L) * 128, g3, be3, hbH);
    }

    // APPNP: h0 = hbH; ping-pong tmpH/apH
    const float2* h0 = hbH;
    const float2* cur = hbH;
    float2* bufs[2] = { tmpH, apH };
    for (int it = 0; it < 10; ++it) {
        float2* o = bufs[it & 1];
        appnp_k<<<AG, 256, 0, stream>>>(cur, h0, offs, edge2, dinv, o);
        cur = o;
    }

    final_k<<<MMG, 256, 0, stream>>>(cur, Wfc, bfc, out);
}

// Round 5
// 674.089 us; speedup vs baseline: 2.9523x; 1.2463x over previous
//
#include <hip/hip_runtime.h>
#include <hip/hip_fp16.h>
#include <cstdint>
#include <cstddef>

#define NN 50000
#define NE 800000
#define HID 64
#define INF_ 128
#define BN_EPS 1e-5f
#define NGRP (NN / 8)        // 6250 node-octets (NN % 8 == 0)
#define SCAN_B 196           // ceil(50000/256)

// ---------------- fp16 pack/unpack ----------------
// float2 carrier = 4 halves; float4 carrier = 8 halves
__device__ __forceinline__ float4 h8_to_f4(float2 raw) {
    union { float f; __half2 h; } ua, ub;
    ua.f = raw.x; ub.f = raw.y;
    float2 fa = __half22float2(ua.h), fb = __half22float2(ub.h);
    return make_float4(fa.x, fa.y, fb.x, fb.y);
}
__device__ __forceinline__ float2 f4_to_h8(float4 v) {
    union { float f; __half2 h; } ua, ub;
    ua.h = __float22half2_rn(make_float2(v.x, v.y));
    ub.h = __float22half2_rn(make_float2(v.z, v.w));
    return make_float2(ua.f, ub.f);
}
struct f8 { float v[8]; };
__device__ __forceinline__ f8 h16_to_f8(float4 raw) {
    f8 r;
    union { float f; __half2 h; } u;
    float2 a;
    u.f = raw.x; a = __half22float2(u.h); r.v[0] = a.x; r.v[1] = a.y;
    u.f = raw.y; a = __half22float2(u.h); r.v[2] = a.x; r.v[3] = a.y;
    u.f = raw.z; a = __half22float2(u.h); r.v[4] = a.x; r.v[5] = a.y;
    u.f = raw.w; a = __half22float2(u.h); r.v[6] = a.x; r.v[7] = a.y;
    return r;
}
__device__ __forceinline__ float4 f8_to_h16(const f8& s) {
    union { float f; __half2 h; } u;
    float4 o;
    u.h = __float22half2_rn(make_float2(s.v[0], s.v[1])); o.x = u.f;
    u.h = __float22half2_rn(make_float2(s.v[2], s.v[3])); o.y = u.f;
    u.h = __float22half2_rn(make_float2(s.v[4], s.v[5])); o.z = u.f;
    u.h = __float22half2_rn(make_float2(s.v[6], s.v[7])); o.w = u.f;
    return o;
}

// ---------------- graph prep ----------------

__global__ void count_k(const int* __restrict__ dst, int* __restrict__ cnt) {
    int e = blockIdx.x * blockDim.x + threadIdx.x;
    if (e < NE) atomicAdd(&cnt[dst[e]], 1);
}

__global__ void dinv_k(const int* __restrict__ cnt, float* __restrict__ dinv) {
    int n = blockIdx.x * blockDim.x + threadIdx.x;
    if (n < NN) dinv[n] = rsqrtf((float)(cnt[n] + 1));   // +1 self-loop
}

// parallel scan of PADDED degrees ((deg+3)&~3) -> offs; 3 kernels
__global__ void scan1_k(const int* __restrict__ cnt, int* __restrict__ offs,
                        int* __restrict__ bsum) {
    __shared__ int sh[256];
    int t = threadIdx.x, i = blockIdx.x * 256 + t;
    int v = (i < NN) ? ((cnt[i] + 3) & ~3) : 0;
    sh[t] = v;
    __syncthreads();
    for (int d = 1; d < 256; d <<= 1) {
        int u = (t >= d) ? sh[t - d] : 0;
        __syncthreads();
        sh[t] += u;
        __syncthreads();
    }
    if (i < NN) offs[i] = sh[t] - v;
    if (t == 255) bsum[blockIdx.x] = sh[255];
}

__global__ void scan2_k(const int* __restrict__ bsum, int* __restrict__ bpre,
                        int* __restrict__ offs) {
    __shared__ int sh[256];
    int t = threadIdx.x;
    int v = (t < SCAN_B) ? bsum[t] : 0;
    sh[t] = v;
    __syncthreads();
    for (int d = 1; d < 256; d <<= 1) {
        int u = (t >= d) ? sh[t - d] : 0;
        __syncthreads();
        sh[t] += u;
        __syncthreads();
    }
    bpre[t] = sh[t] - v;
    if (t == 255) offs[NN] = sh[255];
}

__global__ void scan3_k(int* __restrict__ offs, const int* __restrict__ bpre) {
    int i = blockIdx.x * blockDim.x + threadIdx.x;
    if (i < NN) offs[i] += bpre[i >> 8];
}

__global__ void pad_k(const int* __restrict__ cnt, const int* __restrict__ offs,
                      int2* __restrict__ edge2) {
    int n = blockIdx.x * blockDim.x + threadIdx.x;
    if (n >= NN) return;
    int e = offs[n] + cnt[n], e1 = offs[n + 1];
    for (; e < e1; ++e) edge2[e] = make_int2(0, 0);   // w = 0.0f
}

__global__ void scatter_k(const int* __restrict__ src, const int* __restrict__ dst,
                          const int* __restrict__ offs, int* __restrict__ cursor,
                          const float* __restrict__ dinv,
                          int2* __restrict__ edge2) {
    int e = blockIdx.x * blockDim.x + threadIdx.x;
    if (e < NE) {
        int s = src[e], d = dst[e];
        int pos = offs[d] + atomicAdd(&cursor[d], 1);
        edge2[pos] = make_int2(s, __float_as_int(dinv[s] * dinv[d]));
    }
}

// ---------------- dense matmul: Y[N,64] = X[N,K] @ W[K,64], fp16 out --------
template <int K, bool HIN>
__global__ __launch_bounds__(256) void mm_k(const void* __restrict__ Xv,
                                            const float* __restrict__ W,
                                            float2* __restrict__ Y) {
    const int t = threadIdx.x;
    const int n0 = blockIdx.x * 64;
    const int r0 = (t >> 4) << 2;
    const int c0 = (t & 15) << 2;

    int r[4];
#pragma unroll
    for (int j = 0; j < 4; ++j) {
        int rr = n0 + r0 + j;
        r[j] = rr < NN ? rr : NN - 1;
    }
    const float4* Xr4[4];
    const float2* Xr2[4];
#pragma unroll
    for (int j = 0; j < 4; ++j) {
        if (HIN) Xr2[j] = (const float2*)Xv + (size_t)r[j] * (K / 4);
        else     Xr4[j] = (const float4*)Xv + (size_t)r[j] * (K / 4);
    }

    float acc[4][4];
#pragma unroll
    for (int j = 0; j < 4; ++j)
#pragma unroll
        for (int c = 0; c < 4; ++c) acc[j][c] = 0.f;

#pragma unroll 4
    for (int kq = 0; kq < K / 4; ++kq) {
        float4 xv[4];
#pragma unroll
        for (int j = 0; j < 4; ++j)
            xv[j] = HIN ? h8_to_f4(Xr2[j][kq]) : Xr4[j][kq];
        float4 wv[4];
#pragma unroll
        for (int i = 0; i < 4; ++i)
            wv[i] = *(const float4*)(W + (size_t)(kq * 4 + i) * 64 + c0);
#pragma unroll
        for (int j = 0; j < 4; ++j) {
            acc[j][0] = fmaf(xv[j].x, wv[0].x, acc[j][0]);
            acc[j][1] = fmaf(xv[j].x, wv[0].y, acc[j][1]);
            acc[j][2] = fmaf(xv[j].x, wv[0].z, acc[j][2]);
            acc[j][3] = fmaf(xv[j].x, wv[0].w, acc[j][3]);
            acc[j][0] = fmaf(xv[j].y, wv[1].x, acc[j][0]);
            acc[j][1] = fmaf(xv[j].y, wv[1].y, acc[j][1]);
            acc[j][2] = fmaf(xv[j].y, wv[1].z, acc[j][2]);
            acc[j][3] = fmaf(xv[j].y, wv[1].w, acc[j][3]);
            acc[j][0] = fmaf(xv[j].z, wv[2].x, acc[j][0]);
            acc[j][1] = fmaf(xv[j].z, wv[2].y, acc[j][1]);
            acc[j][2] = fmaf(xv[j].z, wv[2].z, acc[j][2]);
            acc[j][3] = fmaf(xv[j].z, wv[2].w, acc[j][3]);
            acc[j][0] = fmaf(xv[j].w, wv[3].x, acc[j][0]);
            acc[j][1] = fmaf(xv[j].w, wv[3].y, acc[j][1]);
            acc[j][2] = fmaf(xv[j].w, wv[3].z, acc[j][2]);
            acc[j][3] = fmaf(xv[j].w, wv[3].w, acc[j][3]);
        }
    }

#pragma unroll
    for (int j = 0; j < 4; ++j) {
        int rr = n0 + r0 + j;
        if (rr < NN)
            Y[(size_t)rr * 16 + (t & 15)] =
                f4_to_h8(make_float4(acc[j][0], acc[j][1], acc[j][2], acc[j][3]));
    }
}

// ---------------- propagate core: 8 nodes/wave, full-1KB gathers -----------
// lane = slot*8 + fl; slot in [0,8), fl in [0,8) covering feats [fl*8, fl*8+8)
__device__ __forceinline__ void prop_gather8(const float4* __restrict__ X4,
                                             const int2* __restrict__ E,
                                             int e0, int e1, int fl,
                                             float acc[8]) {
    for (int e = e0; e < e1; e += 4) {   // padded: e1-e0 multiple of 4
        int2 d0 = E[e], d1 = E[e + 1], d2 = E[e + 2], d3 = E[e + 3];
        float4 r0 = X4[(size_t)d0.x * 8 + fl];
        float4 r1 = X4[(size_t)d1.x * 8 + fl];
        float4 r2 = X4[(size_t)d2.x * 8 + fl];
        float4 r3 = X4[(size_t)d3.x * 8 + fl];
        float w0 = __int_as_float(d0.y), w1 = __int_as_float(d1.y);
        float w2 = __int_as_float(d2.y), w3 = __int_as_float(d3.y);
        f8 x0 = h16_to_f8(r0), x1 = h16_to_f8(r1);
        f8 x2 = h16_to_f8(r2), x3 = h16_to_f8(r3);
#pragma unroll
        for (int j = 0; j < 8; ++j) {
            acc[j] = fmaf(w0, x0.v[j], acc[j]);
            acc[j] = fmaf(w1, x1.v[j], acc[j]);
            acc[j] = fmaf(w2, x2.v[j], acc[j]);
            acc[j] = fmaf(w3, x3.v[j], acc[j]);
        }
    }
}

// ---------------- propagate + bias + BN-stats (fp16 in, fp16 out) ----------
__global__ __launch_bounds__(256) void prop_stats_k(
        const float4* __restrict__ X4, const int* __restrict__ offs,
        const int2* __restrict__ edge2, const float* __restrict__ dinv,
        const float* __restrict__ bias, float4* __restrict__ Y4,
        float* __restrict__ stats) {
    const int lane = threadIdx.x & 63;
    const int wave = threadIdx.x >> 6;
    const int slot = lane >> 3;
    const int fl = lane & 7;
    const int wid = blockIdx.x * 4 + wave;
    const int nw = gridDim.x * 4;

    float bias8[8];
    {
        float4 b0 = ((const float4*)bias)[fl * 2];
        float4 b1 = ((const float4*)bias)[fl * 2 + 1];
        bias8[0] = b0.x; bias8[1] = b0.y; bias8[2] = b0.z; bias8[3] = b0.w;
        bias8[4] = b1.x; bias8[5] = b1.y; bias8[6] = b1.z; bias8[7] = b1.w;
    }

    float s1[8], s2[8];
#pragma unroll
    for (int j = 0; j < 8; ++j) { s1[j] = 0.f; s2[j] = 0.f; }

    for (int g = wid; g < NGRP; g += nw) {
        int n = g * 8 + slot;
        float dn = dinv[n];
        float dd = dn * dn;
        f8 self = h16_to_f8(X4[(size_t)n * 8 + fl]);
        float acc[8];
#pragma unroll
        for (int j = 0; j < 8; ++j) acc[j] = dd * self.v[j];
        int e0 = offs[n], e1 = offs[n + 1];
        prop_gather8(X4, edge2, e0, e1, fl, acc);
        f8 o;
#pragma unroll
        for (int j = 0; j < 8; ++j) {
            acc[j] += bias8[j];
            o.v[j] = acc[j];
            s1[j] += acc[j];
            s2[j] = fmaf(acc[j], acc[j], s2[j]);
        }
        Y4[(size_t)n * 8 + fl] = f8_to_h16(o);
    }

    // reduce across the 8 slots (lanes differing in bits 3,4,5)
#pragma unroll
    for (int m = 8; m <= 32; m <<= 1) {
#pragma unroll
        for (int j = 0; j < 8; ++j) {
            s1[j] += __shfl_xor(s1[j], m, 64);
            s2[j] += __shfl_xor(s2[j], m, 64);
        }
    }

    __shared__ float red[4][8][16];
    if (lane < 8) {
#pragma unroll
        for (int j = 0; j < 8; ++j) {
            red[wave][lane][j] = s1[j];
            red[wave][lane][8 + j] = s2[j];
        }
    }
    __syncthreads();
    int t = threadIdx.x;
    if (t < 128) {
        int j = t & 63;            // feature index
        int isq = t >> 6;          // 0 = sum, 1 = sumsq
        int fli = j >> 3, c = (j & 7) + isq * 8;
        float a = red[0][fli][c] + red[1][fli][c] + red[2][fli][c] + red[3][fli][c];
        atomicAdd(&stats[isq * 64 + j], a);
    }
}

// ---------------- batchnorm + relu: fp16 in -> fp16 out ----------------
__global__ void bn_relu_k(const float4* __restrict__ Y4, const float* __restrict__ stats,
                          const float* __restrict__ g, const float* __restrict__ be,
                          float4* __restrict__ H4) {
    int i = blockIdx.x * blockDim.x + threadIdx.x;
    if (i >= NN * 8) return;
    int fg = i & 7;
    const float invN = 1.f / (float)NN;
    float4 sm0 = ((const float4*)stats)[fg * 2];
    float4 sm1 = ((const float4*)stats)[fg * 2 + 1];
    float4 sq0 = ((const float4*)(stats + 64))[fg * 2];
    float4 sq1 = ((const float4*)(stats + 64))[fg * 2 + 1];
    float4 gv0 = ((const float4*)g)[fg * 2];
    float4 gv1 = ((const float4*)g)[fg * 2 + 1];
    float4 bv0 = ((const float4*)be)[fg * 2];
    float4 bv1 = ((const float4*)be)[fg * 2 + 1];
    float sm[8] = { sm0.x, sm0.y, sm0.z, sm0.w, sm1.x, sm1.y, sm1.z, sm1.w };
    float sq[8] = { sq0.x, sq0.y, sq0.z, sq0.w, sq1.x, sq1.y, sq1.z, sq1.w };
    float gv[8] = { gv0.x, gv0.y, gv0.z, gv0.w, gv1.x, gv1.y, gv1.z, gv1.w };
    float bv[8] = { bv0.x, bv0.y, bv0.z, bv0.w, bv1.x, bv1.y, bv1.z, bv1.w };
    f8 y = h16_to_f8(Y4[i]);
    f8 o;
#pragma unroll
    for (int j = 0; j < 8; ++j) {
        float m = sm[j] * invN;
        float v = sq[j] * invN - m * m;
        float val = fmaf(gv[j] * rsqrtf(v + BN_EPS), y.v[j] - m, bv[j]);
        o.v[j] = val > 0.f ? val : 0.f;
    }
    H4[i] = f8_to_h16(o);
}

// ---------------- APPNP iteration (fp16, 8 nodes/wave) ----------------
__global__ __launch_bounds__(256) void appnp_k(
        const float4* __restrict__ X4, const float4* __restrict__ H04,
        const int* __restrict__ offs, const int2* __restrict__ edge2,
        const float* __restrict__ dinv, float4* __restrict__ Y4) {
    const int lane = threadIdx.x & 63;
    const int wave = threadIdx.x >> 6;
    const int slot = lane >> 3;
    const int fl = lane & 7;
    const int wid = blockIdx.x * 4 + wave;
    if (wid >= NGRP) return;
    int n = wid * 8 + slot;
    float dn = dinv[n];
    float dd = dn * dn;
    f8 self = h16_to_f8(X4[(size_t)n * 8 + fl]);
    float acc[8];
#pragma unroll
    for (int j = 0; j < 8; ++j) acc[j] = dd * self.v[j];
    int e0 = offs[n], e1 = offs[n + 1];
    prop_gather8(X4, edge2, e0, e1, fl, acc);
    f8 h0 = h16_to_f8(H04[(size_t)n * 8 + fl]);
    f8 o;
#pragma unroll
    for (int j = 0; j < 8; ++j)
        o.v[j] = fmaf(0.9f, acc[j], 0.1f * h0.v[j]);
    Y4[(size_t)n * 8 + fl] = f8_to_h16(o);
}

// ---------------- FC + log_softmax (fp16 in, fp32 out) ----------------
__global__ __launch_bounds__(256) void final_k(const float2* __restrict__ H2,
                                               const float* __restrict__ Wfc,
                                               const float* __restrict__ bfc,
                                               float* __restrict__ out) {
    const int t = threadIdx.x;
    const int n0 = blockIdx.x * 64;
    const int r0 = (t >> 4) << 2;
    const int c0 = (t & 15) << 2;

    int r[4];
#pragma unroll
    for (int j = 0; j < 4; ++j) {
        int rr = n0 + r0 + j;
        r[j] = rr < NN ? rr : NN - 1;
    }
    const float2* Xr[4];
#pragma unroll
    for (int j = 0; j < 4; ++j) Xr[j] = H2 + (size_t)r[j] * 16;

    float4 bf = *(const float4*)(bfc + c0);
    float acc[4][4];
#pragma unroll
    for (int j = 0; j < 4; ++j) {
        acc[j][0] = bf.x; acc[j][1] = bf.y; acc[j][2] = bf.z; acc[j][3] = bf.w;
    }

#pragma unroll 4
    for (int kq = 0; kq < 16; ++kq) {
        float4 xv[4];
#pragma unroll
        for (int j = 0; j < 4; ++j) xv[j] = h8_to_f4(Xr[j][kq]);
        float4 wv[4];
#pragma unroll
        for (int i = 0; i < 4; ++i)
            wv[i] = *(const float4*)(Wfc + (size_t)(kq * 4 + i) * 64 + c0);
#pragma unroll
        for (int j = 0; j < 4; ++j) {
            acc[j][0] = fmaf(xv[j].x, wv[0].x, acc[j][0]);
            acc[j][1] = fmaf(xv[j].x, wv[0].y, acc[j][1]);
            acc[j][2] = fmaf(xv[j].x, wv[0].z, acc[j][2]);
            acc[j][3] = fmaf(xv[j].x, wv[0].w, acc[j][3]);
            acc[j][0] = fmaf(xv[j].y, wv[1].x, acc[j][0]);
            acc[j][1] = fmaf(xv[j].y, wv[1].y, acc[j][1]);
            acc[j][2] = fmaf(xv[j].y, wv[1].z, acc[j][2]);
            acc[j][3] = fmaf(xv[j].y, wv[1].w, acc[j][3]);
            acc[j][0] = fmaf(xv[j].z, wv[2].x, acc[j][0]);
            acc[j][1] = fmaf(xv[j].z, wv[2].y, acc[j][1]);
            acc[j][2] = fmaf(xv[j].z, wv[2].z, acc[j][2]);
            acc[j][3] = fmaf(xv[j].z, wv[2].w, acc[j][3]);
            acc[j][0] = fmaf(xv[j].w, wv[3].x, acc[j][0]);
            acc[j][1] = fmaf(xv[j].w, wv[3].y, acc[j][1]);
            acc[j][2] = fmaf(xv[j].w, wv[3].z, acc[j][2]);
            acc[j][3] = fmaf(xv[j].w, wv[3].w, acc[j][3]);
        }
    }

#pragma unroll
    for (int j = 0; j < 4; ++j) {
        float m = fmaxf(fmaxf(acc[j][0], acc[j][1]), fmaxf(acc[j][2], acc[j][3]));
#pragma unroll
        for (int d = 1; d <= 8; d <<= 1) m = fmaxf(m, __shfl_xor(m, d, 64));
        float s = expf(acc[j][0] - m) + expf(acc[j][1] - m) +
                  expf(acc[j][2] - m) + expf(acc[j][3] - m);
#pragma unroll
        for (int d = 1; d <= 8; d <<= 1) s += __shfl_xor(s, d, 64);
        float lse = m + logf(s);
        int rr = n0 + r0 + j;
        if (rr < NN)
            *(float4*)(out + (size_t)rr * 64 + c0) =
                make_float4(acc[j][0] - lse, acc[j][1] - lse,
                            acc[j][2] - lse, acc[j][3] - lse);
    }
}

// ---------------- host launch ----------------

static inline char* alignup(char* p, size_t a) {
    return (char*)(((uintptr_t)p + a - 1) & ~(uintptr_t)(a - 1));
}

extern "C" void kernel_launch(void* const* d_in, const int* in_sizes, int n_in,
                              void* d_out, int out_size, void* d_ws, size_t ws_size,
                              hipStream_t stream) {
    const float* x   = (const float*)d_in[0];
    const int*   ei  = (const int*)d_in[1];
    const float* W1  = (const float*)d_in[2];
    const float* b1  = (const float*)d_in[3];
    const float* W2  = (const float*)d_in[4];
    const float* b2  = (const float*)d_in[5];
    const float* Wx  = (const float*)d_in[6];
    const float* bx  = (const float*)d_in[7];
    const float* g1  = (const float*)d_in[8];
    const float* be1 = (const float*)d_in[9];
    const float* g2  = (const float*)d_in[10];
    const float* be2 = (const float*)d_in[11];
    const float* g3  = (const float*)d_in[12];
    const float* be3 = (const float*)d_in[13];
    const float* Wfc = (const float*)d_in[14];
    const float* bfc = (const float*)d_in[15];
    float* out = (float*)d_out;

    const int* srcA = ei;
    const int* dstA = ei + NE;

    char* p = (char*)d_ws;
    int*   deg    = (int*)p;   p += NN * 4;
    int*   cursor = (int*)p;   p += NN * 4;
    float* stats  = (float*)p; p += 512 * 4;
    size_t zbytes = (size_t)(p - (char*)d_ws);
    p = alignup(p, 512);
    int*   offs  = (int*)p;    p += (NN + 4) * 4;   p = alignup(p, 512);
    float* dinv  = (float*)p;  p += NN * 4;         p = alignup(p, 512);
    int*   bsum  = (int*)p;    p += 256 * 4;
    int*   bpre  = (int*)p;    p += 256 * 4;        p = alignup(p, 512);
    int2*  edge2 = (int2*)p;   p += ((size_t)NE + 3 * NN + 256) * 8; p = alignup(p, 512);
    float4* tmpH = (float4*)p; p += (size_t)NN * 64 * 2; p = alignup(p, 512);
    float4* hbH  = (float4*)p; p += (size_t)NN * 64 * 2; p = alignup(p, 512);
    float4* apH  = (float4*)p; p += (size_t)NN * 64 * 2; p = alignup(p, 512);
    float4* pbH  = (float4*)p; p += (size_t)NN * 64 * 2;

    hipMemsetAsync(d_ws, 0, zbytes, stream);

    count_k<<<(NE + 255) / 256, 256, 0, stream>>>(dstA, deg);
    dinv_k<<<(NN + 255) / 256, 256, 0, stream>>>(deg, dinv);
    scan1_k<<<SCAN_B, 256, 0, stream>>>(deg, offs, bsum);
    scan2_k<<<1, 256, 0, stream>>>(bsum, bpre, offs);
    scan3_k<<<(NN + 255) / 256, 256, 0, stream>>>(offs, bpre);
    pad_k<<<(NN + 255) / 256, 256, 0, stream>>>(deg, offs, edge2);
    scatter_k<<<(NE + 255) / 256, 256, 0, stream>>>(srcA, dstA, offs, cursor, dinv, edge2);

    const int MMG = (NN + 63) / 64;          // 782
    const int PG  = (NGRP + 3) / 4;          // 1563: one octet per wave
    const int BNG = (NN * 8 + 255) / 256;    // 1563

    mm_k<INF_, false><<<MMG, 256, 0, stream>>>(x, W1, (float2*)tmpH);
    prop_stats_k<<<PG, 256, 0, stream>>>(tmpH, offs, edge2, dinv, b1, pbH, stats + 0 * 128);
    bn_relu_k<<<BNG, 256, 0, stream>>>(pbH, stats + 0 * 128, g1, be1, hbH);

    mm_k<HID, true><<<MMG, 256, 0, stream>>>(hbH, W2, (float2*)tmpH);
    prop_stats_k<<<PG, 256, 0, stream>>>(tmpH, offs, edge2, dinv, b2, pbH, stats + 1 * 128);
    bn_relu_k<<<BNG, 256, 0, stream>>>(pbH, stats + 1 * 128, g2, be2, hbH);

    for (int L = 0; L < 2; ++L) {
        mm_k<HID, true><<<MMG, 256, 0, stream>>>(hbH, Wx + (size_t)L * 64 * 64, (float2*)tmpH);
        prop_stats_k<<<PG, 256, 0, stream>>>(tmpH, offs, edge2, dinv, bx + (size_t)L * 64,
                                             pbH, stats + (2 + L) * 128);
        bn_relu_k<<<BNG, 256, 0, stream>>>(pbH, stats + (2 + L) * 128, g3, be3, hbH);
    }

    // APPNP: h0 = hbH; ping-pong tmpH/apH
    const float4* h0 = hbH;
    const float4* cur = hbH;
    float4* bufs[2] = { tmpH, apH };
    for (int it = 0; it < 10; ++it) {
        float4* o = bufs[it & 1];
        appnp_k<<<PG, 256, 0, stream>>>(cur, h0, offs, edge2, dinv, o);
        cur = o;
    }

    final_k<<<MMG, 256, 0, stream>>>((const float2*)cur, Wfc, bfc, out);
}